// Round 3
// baseline (564.206 us; speedup 1.0000x reference)
//
#include <hip/hip_runtime.h>

typedef unsigned short u16;
typedef __attribute__((ext_vector_type(8)))  short          short8;
typedef __attribute__((ext_vector_type(8)))  unsigned short ushort8v;
typedef __attribute__((ext_vector_type(4)))  unsigned short ushort4v;
typedef __attribute__((ext_vector_type(16))) float          float16v;

__device__ __forceinline__ float bf2f(u16 u){
  union { unsigned int i; float f; } x; x.i = ((unsigned int)u) << 16; return x.f;
}
__device__ __forceinline__ u16 f2bf(float f){
  union { float f; unsigned int i; } x; x.f = f;
  unsigned int u = x.i;
  unsigned int r = (u + 0x7FFFu + ((u >> 16) & 1u)) >> 16;
  return (u16)r;
}
__device__ __forceinline__ float lk(float v){ return v > 0.f ? v : 0.01f*v; }

// ---------------- weight permute+quantize: Wmat[o][j*C+c] = bf16(W[o][c][j]) --
// ws layout (bf16 elems): Wmat1 @0 (256x384), Wmat2 @98304 (128x768), Wmat3 @196608 (64x384)
__global__ void permute_w(const float* __restrict__ W1, const float* __restrict__ W2,
                          const float* __restrict__ W3, u16* __restrict__ ws){
  int t = blockIdx.x*256 + threadIdx.x;
  const float* src; u16* dst; int C, local;
  if (t < 98304)       { src = W1; dst = ws;          C = 128; local = t; }
  else if (t < 196608) { src = W2; dst = ws + 98304;  C = 256; local = t - 98304; }
  else if (t < 221184) { src = W3; dst = ws + 196608; C = 128; local = t - 196608; }
  else return;
  int K3 = 3*C;
  int o = local / K3, r = local - o*K3;
  int j = r / C,      c = r - j*C;
  dst[local] = f2bf(src[o*K3 + c*3 + j]);
}

// ---------------- fused per-tree layer (8 waves) ----------------
// GEMM out[O x 127] = Wmat[O x 3C] * G, where G[j*C+c][m] = bIn[idx[3m+j]][c]
// Work units: (O/(32*PAIR) row-blocks) x (4 n-tiles) = 8*UPW units, UPW per wave.
// Units of one wave share the same row-block (A-fragment reuse across n-tiles).
template<int CIN, int O, int SIN, int OST, int PAIR, bool LEAKY, bool IS_L3>
__device__ __forceinline__ void do_layer(const u16* __restrict__ Wm,
                                         const float* __restrict__ bias,
                                         const u16* bIn, u16* bOut, float* bOutF,
                                         const int* sidx, float* sstat,
                                         int tid, float* out_mean, float* out_inv)
{
  constexpr int K3   = 3*CIN;
  constexpr int KS   = CIN/16;          // k-steps per j segment
  constexpr int NJK  = K3/16;           // total k-steps
  constexpr int ROWS = 32*PAIR;
  constexpr int U    = (O/ROWS)*4;
  constexpr int UPW  = U/8;             // units per wave (>=1)
  static_assert(UPW >= 1, "need >=1 unit per wave");
  const int w = tid >> 6, lane = tid & 63, l31 = lane & 31, h = lane >> 5;

  const int u0   = w*UPW;
  const int pair = u0 >> 2;             // row-block id (same for all this wave's units)
  const int nt0  = u0 & 3;              // first n-tile
  const int r0   = pair * ROWS;

  const u16* aP[PAIR];
#pragma unroll
  for (int a = 0; a < PAIR; ++a)
    aP[a] = Wm + (size_t)(r0 + a*32 + l31)*K3 + h*8;

  // bias cache (fp32), layout mirrors C/D rows this lane will produce
  float bv[PAIR][4][4];
#pragma unroll
  for (int a = 0; a < PAIR; ++a)
#pragma unroll
    for (int g = 0; g < 4; ++g){
      const int rowb = r0 + a*32 + 8*g + 4*h;
#pragma unroll
      for (int q = 0; q < 4; ++q) bv[a][g][q] = bias[rowb + q];
    }

  int boff[UPW][3];
#pragma unroll
  for (int k = 0; k < UPW; ++k){
    int m = (nt0 + k)*32 + l31;         // position 0..127 (127 is pad, masked below)
#pragma unroll
    for (int j = 0; j < 3; ++j){
      int i = sidx[3*m + j];            // m==127 hits zero-padded sidx[381..383]
      boff[k][j] = i*SIN + h*8;
    }
  }

  float16v acc[UPW][PAIR];
#pragma unroll
  for (int k = 0; k < UPW; ++k)
#pragma unroll
    for (int a = 0; a < PAIR; ++a) acc[k][a] = {};

#pragma unroll
  for (int jk = 0; jk < NJK; ++jk){
    const int j    = jk / KS;
    const int coff = (jk - j*KS)*16;
    short8 A[PAIR];
#pragma unroll
    for (int a = 0; a < PAIR; ++a) A[a] = *(const short8*)(aP[a] + jk*16);
#pragma unroll
    for (int k = 0; k < UPW; ++k){
      short8 Bf = *(const short8*)(bIn + boff[k][j] + coff);
#pragma unroll
      for (int a = 0; a < PAIR; ++a)
        acc[k][a] = __builtin_amdgcn_mfma_f32_32x32x16_bf16(A[a], Bf, acc[k][a], 0, 0, 0);
    }
  }

  // add bias; stats partials (+ raw fp32 store for L3)
  float s = 0.f, s2 = 0.f;
#pragma unroll
  for (int k = 0; k < UPW; ++k){
    const int m = (nt0 + k)*32 + l31;
    const bool valid = (m <= 126);
#pragma unroll
    for (int a = 0; a < PAIR; ++a){
#pragma unroll
      for (int g = 0; g < 4; ++g){
        const int rowb = r0 + a*32 + 8*g + 4*h;   // C/D row = (reg&3)+8*(reg>>2)+4h
#pragma unroll
        for (int q = 0; q < 4; ++q){
          float raw = acc[k][a][4*g + q] + bv[a][g][q];
          acc[k][a][4*g + q] = raw;
          if (valid){
            s += raw; s2 += raw*raw;
            if constexpr (IS_L3) bOutF[(size_t)(m+1)*OST + rowb + q] = raw;
          }
        }
      }
    }
  }

  // block-wide stats (8 waves)
#pragma unroll
  for (int off = 32; off >= 1; off >>= 1){
    s  += __shfl_down(s,  off, 64);
    s2 += __shfl_down(s2, off, 64);
  }
  if (lane == 0){ sstat[w*2] = s; sstat[w*2+1] = s2; }
  __syncthreads();

  float tot = 0.f, tot2 = 0.f;
#pragma unroll
  for (int i = 0; i < 8; ++i){ tot += sstat[2*i]; tot2 += sstat[2*i+1]; }
  constexpr float CNT = (float)(O * 128);
  const float mean = tot / CNT;
  float var = (tot2 - tot*mean) / (CNT - 1.f);   // unbiased, ddof=1
  var = fmaxf(var, 0.f);
  const float inv = 1.f / (sqrtf(var) + 1e-5f);
  *out_mean = mean; *out_inv = inv;

  if constexpr (!IS_L3){
    // normalized(+leaky) bf16 straight from acc (single quantization)
#pragma unroll
    for (int k = 0; k < UPW; ++k){
      const int m = (nt0 + k)*32 + l31;
      const bool valid = (m <= 126);
#pragma unroll
      for (int a = 0; a < PAIR; ++a){
#pragma unroll
        for (int g = 0; g < 4; ++g){
          const int rowb = r0 + a*32 + 8*g + 4*h;
          ushort4v pk;
#pragma unroll
          for (int q = 0; q < 4; ++q){
            float f = (acc[k][a][4*g + q] - mean) * inv;
            if constexpr (LEAKY) f = lk(f);
            pk[q] = f2bf(f);
          }
          if (valid) *(ushort4v*)(bOut + (size_t)(m+1)*OST + rowb) = pk;
        }
      }
    }
    // node-0 row: normalized zero
    if (tid < O/8){
      float f0 = (0.f - mean) * inv;
      if constexpr (LEAKY) f0 = lk(f0);
      const u16 v0 = f2bf(f0);
      ushort8v z;
#pragma unroll
      for (int e = 0; e < 8; ++e) z[e] = v0;
      *(ushort8v*)(bOut + tid*8) = z;
    }
  }
  __syncthreads();
}

__global__ __launch_bounds__(512, 1) void bao_main(
    const float* __restrict__ trees, const int* __restrict__ gidx,
    const u16* __restrict__ wsW,
    const float* __restrict__ b1, const float* __restrict__ b2, const float* __restrict__ b3,
    const float* __restrict__ W4, const float* __restrict__ b4,
    const float* __restrict__ W5, const float* __restrict__ b5,
    float* __restrict__ dout)
{
  __shared__ __align__(16) u16 bufS[128*136];   // small ping buffer (C<=128, +8 pad)
  __shared__ __align__(16) u16 bufL[128*264];   // large pong buffer (C=256, +8 pad)
  __shared__ int   sidx[384];
  __shared__ float sstat[16];
  __shared__ float spoolP[256];
  __shared__ float spool[64];
  __shared__ float sh[32];

  const int tid = threadIdx.x;
  const int b = blockIdx.x;
  float* bufF = (float*)bufL;                   // layer-3 raw fp32 out, stride 67 (odd -> conflict-free)

  // load + transpose + quantize trees[b] (fp32 [128 c][128 n] -> bf16 bufS[n][c]).
  // Nodes interleaved at stride 32 so concurrent ds_write_b128 hit all 8
  // 16B super-banks (node-stride 17 super-banks, lane-step 17 ≡ 1 mod 8).
  const float* tb = trees + (size_t)b * (128*128);
  {
    const int cgrp = tid >> 5, ngrp = tid & 31;
    const int c0 = cgrp*8;
#pragma unroll
    for (int nn = 0; nn < 4; ++nn){
      const int n = ngrp + 32*nn;
      ushort8v pk;
#pragma unroll
      for (int cc = 0; cc < 8; ++cc) pk[cc] = f2bf(tb[(c0 + cc)*128 + n]);
      *(ushort8v*)(bufS + n*136 + c0) = pk;
    }
  }
  // idx (381 entries, pad to 384 with 0)
  if (tid < 96){
#pragma unroll
    for (int k = 0; k < 4; ++k){
      int ii = tid*4 + k;
      sidx[ii] = (ii < 381) ? gidx[(size_t)b*381 + ii] : 0;
    }
  }
  __syncthreads();

  float mean, inv;
  do_layer<128,256,136,264,2,true ,false>(wsW,          b1, bufS, bufL, nullptr, sidx, sstat, tid, &mean, &inv);
  do_layer<256,128,264,136,2,true ,false>(wsW + 98304,  b2, bufL, bufS, nullptr, sidx, sstat, tid, &mean, &inv);
  do_layer<128, 64,136, 67,1,false,true >(wsW + 196608, b3, bufS, nullptr, bufF,  sidx, sstat, tid, &mean, &inv);

  // max-pool over nodes (raw fp32 in bufF); node-0 raw is exactly 0, so
  // flooring each segment partial at 0 is exact. Normalization is monotone:
  // max(normalized) = (max(raw) - mean)*inv.
  if (tid < 256){
    const int ch = tid & 63, seg = tid >> 6;
    float mx = 0.f;
    const int nd0 = seg*32 + (seg == 0 ? 1 : 0);
    for (int nd = nd0; nd < seg*32 + 32; ++nd) mx = fmaxf(mx, bufF[nd*67 + ch]);
    spoolP[seg*64 + ch] = mx;
  }
  __syncthreads();
  if (tid < 64){
    float mx = fmaxf(fmaxf(spoolP[tid], spoolP[64 + tid]),
                     fmaxf(spoolP[128 + tid], spoolP[192 + tid]));
    spool[tid] = (mx - mean) * inv;
  }
  __syncthreads();
  if (tid < 32){
    float a = b4[tid];
    for (int c = 0; c < 64; ++c) a += spool[c] * W4[tid*64 + c];
    sh[tid] = lk(a);
  }
  __syncthreads();
  if (tid == 0){
    float o = b5[0];
    for (int i = 0; i < 32; ++i) o += sh[i] * W5[i];
    dout[b] = o;
  }
}

extern "C" void kernel_launch(void* const* d_in, const int* in_sizes, int n_in,
                              void* d_out, int out_size, void* d_ws, size_t ws_size,
                              hipStream_t stream) {
  const float* trees = (const float*)d_in[0];
  const int*   gidx  = (const int*)d_in[1];
  const float* W1 = (const float*)d_in[2];
  const float* b1 = (const float*)d_in[3];
  const float* W2 = (const float*)d_in[4];
  const float* b2 = (const float*)d_in[5];
  const float* W3 = (const float*)d_in[6];
  const float* b3 = (const float*)d_in[7];
  const float* W4 = (const float*)d_in[8];
  const float* b4 = (const float*)d_in[9];
  const float* W5 = (const float*)d_in[10];
  const float* b5 = (const float*)d_in[11];
  u16* wsW = (u16*)d_ws;   // 221184 bf16 elems = 432 KB of permuted+quantized weights

  permute_w<<<864, 256, 0, stream>>>(W1, W2, W3, wsW);
  bao_main<<<2048, 512, 0, stream>>>(trees, gidx, wsW, b1, b2, b3, W4, b4, W5, b5,
                                     (float*)d_out);
}

// Round 4
// 393.952 us; speedup vs baseline: 1.4322x; 1.4322x over previous
//
#include <hip/hip_runtime.h>

typedef unsigned short u16;
typedef __attribute__((ext_vector_type(8)))  short          short8;
typedef __attribute__((ext_vector_type(8)))  unsigned short ushort8v;
typedef __attribute__((ext_vector_type(4)))  unsigned short ushort4v;
typedef __attribute__((ext_vector_type(16))) float          float16v;

__device__ __forceinline__ float bf2f(u16 u){
  union { unsigned int i; float f; } x; x.i = ((unsigned int)u) << 16; return x.f;
}
__device__ __forceinline__ u16 f2bf(float f){
  union { float f; unsigned int i; } x; x.f = f;
  unsigned int u = x.i;
  unsigned int r = (u + 0x7FFFu + ((u >> 16) & 1u)) >> 16;
  return (u16)r;
}
__device__ __forceinline__ float lk(float v){ return v > 0.f ? v : 0.01f*v; }

// ---------------- weight permute+quantize: Wmat[o][j*C+c] = bf16(W[o][c][j]) --
// ws layout (bf16 elems): Wmat1 @0 (256x384), Wmat2 @98304 (128x768), Wmat3 @196608 (64x384)
__global__ void permute_w(const float* __restrict__ W1, const float* __restrict__ W2,
                          const float* __restrict__ W3, u16* __restrict__ ws){
  int t = blockIdx.x*256 + threadIdx.x;
  const float* src; u16* dst; int C, local;
  if (t < 98304)       { src = W1; dst = ws;          C = 128; local = t; }
  else if (t < 196608) { src = W2; dst = ws + 98304;  C = 256; local = t - 98304; }
  else if (t < 221184) { src = W3; dst = ws + 196608; C = 128; local = t - 196608; }
  else return;
  int K3 = 3*C;
  int o = local / K3, r = local - o*K3;
  int j = r / C,      c = r - j*C;
  dst[local] = f2bf(src[o*K3 + c*3 + j]);
}

// ---------------- fused per-tree layer (4 waves, in-register output) ----------
// GEMM out[O x 127] = Wmat[O x 3C] * G, where G[j*C+c][m] = bIn[idx[3m+j]][c]
// Round-2 split: wave w -> row-pair (w*P)>>2 (64 rows), n-tiles (w*P)&3 ..+NTL.
// Output stays in acc until after the stats __syncthreads (which fences all
// k-loop LDS reads), THEN is written to bOut/bOutF — which may ALIAS bIn.
template<int CIN, int O, int SIN, int OST, bool LEAKY, bool IS_L3>
__device__ __forceinline__ void do_layer(const u16* __restrict__ Wm,
                                         const float* __restrict__ bias,
                                         const u16* bIn, u16* bOut, float* bOutF,
                                         const int* sidx, float* sstat,
                                         int tid, float* out_mean, float* out_inv)
{
  constexpr int K3  = 3*CIN;
  constexpr int KS  = CIN/16;     // k-steps per j segment
  constexpr int NJK = K3/16;      // total k-steps
  constexpr int P   = O/64;       // row-pairs; also n-tiles per wave
  constexpr int NTL = P;
  const int w = tid >> 6, lane = tid & 63, l31 = lane & 31, h = lane >> 5;

  const int pair = (w*P) >> 2;    // which 64-row pair of Wmat
  const int nt0  = (w*P) & 3;     // first 32-col n-tile
  const int r0   = pair * 64;

  const u16* a0p = Wm + (size_t)(r0 + l31)*K3 + h*8;
  const u16* a1p = a0p + 32*K3;

  int boff[NTL][3];
#pragma unroll
  for (int n = 0; n < NTL; ++n){
    int m = (nt0 + n)*32 + l31;   // position 0..127 (127 is pad, masked below)
#pragma unroll
    for (int j = 0; j < 3; ++j){
      int i = sidx[3*m + j];      // m==127 hits zero-padded sidx[381..383]
      boff[n][j] = i*SIN + h*8;
    }
  }

  float16v acc[NTL][2];
#pragma unroll
  for (int n = 0; n < NTL; ++n){ acc[n][0] = {}; acc[n][1] = {}; }

#pragma unroll
  for (int jk = 0; jk < NJK; ++jk){
    const int j    = jk / KS;
    const int coff = (jk - j*KS)*16;
    short8 A0 = *(const short8*)(a0p + jk*16);
    short8 A1 = *(const short8*)(a1p + jk*16);
#pragma unroll
    for (int n = 0; n < NTL; ++n){
      short8 Bf = *(const short8*)(bIn + boff[n][j] + coff);
      acc[n][0] = __builtin_amdgcn_mfma_f32_32x32x16_bf16(A0, Bf, acc[n][0], 0, 0, 0);
      acc[n][1] = __builtin_amdgcn_mfma_f32_32x32x16_bf16(A1, Bf, acc[n][1], 0, 0, 0);
    }
  }

  // post-loop: bias (L2-hot, off the k-loop critical path), add, stats partials
  float bv[2][4][4];
#pragma unroll
  for (int a = 0; a < 2; ++a)
#pragma unroll
    for (int g = 0; g < 4; ++g){
      const int rowb = r0 + a*32 + 8*g + 4*h;
#pragma unroll
      for (int q = 0; q < 4; ++q) bv[a][g][q] = bias[rowb + q];
    }

  float s = 0.f, s2 = 0.f;
#pragma unroll
  for (int n = 0; n < NTL; ++n){
    const int m = (nt0 + n)*32 + l31;
    const bool valid = (m <= 126);
#pragma unroll
    for (int a = 0; a < 2; ++a)
#pragma unroll
      for (int g = 0; g < 4; ++g)
#pragma unroll
        for (int q = 0; q < 4; ++q){
          float raw = acc[n][a][4*g + q] + bv[a][g][q];
          acc[n][a][4*g + q] = raw;
          if (valid){ s += raw; s2 += raw*raw; }
        }
  }

  // block-wide stats; this __syncthreads also FENCES all k-loop reads of bIn,
  // making it safe for the store phase below to overwrite bIn's region.
#pragma unroll
  for (int off = 32; off >= 1; off >>= 1){
    s  += __shfl_down(s,  off, 64);
    s2 += __shfl_down(s2, off, 64);
  }
  if (lane == 0){ sstat[w*2] = s; sstat[w*2+1] = s2; }
  __syncthreads();

  const float tot  = sstat[0] + sstat[2] + sstat[4] + sstat[6];
  const float tot2 = sstat[1] + sstat[3] + sstat[5] + sstat[7];
  constexpr float CNT = (float)(O * 128);
  const float mean = tot / CNT;
  float var = (tot2 - tot*mean) / (CNT - 1.f);   // unbiased, ddof=1
  var = fmaxf(var, 0.f);
  const float inv = 1.f / (sqrtf(var) + 1e-5f);
  *out_mean = mean; *out_inv = inv;

  // store phase (may alias the dead input region)
  if constexpr (!IS_L3){
#pragma unroll
    for (int n = 0; n < NTL; ++n){
      const int m = (nt0 + n)*32 + l31;
      const bool valid = (m <= 126);
#pragma unroll
      for (int a = 0; a < 2; ++a){
#pragma unroll
        for (int g = 0; g < 4; ++g){
          const int rowb = r0 + a*32 + 8*g + 4*h;
          ushort4v pk;
#pragma unroll
          for (int q = 0; q < 4; ++q){
            float f = (acc[n][a][4*g + q] - mean) * inv;
            if constexpr (LEAKY) f = lk(f);
            pk[q] = f2bf(f);
          }
          if (valid) *(ushort4v*)(bOut + (size_t)(m+1)*OST + rowb) = pk;
        }
      }
    }
    // node-0 row: normalized zero
    if (tid < O/8){
      float f0 = (0.f - mean) * inv;
      if constexpr (LEAKY) f0 = lk(f0);
      const u16 v0 = f2bf(f0);
      ushort8v z;
#pragma unroll
      for (int e = 0; e < 8; ++e) z[e] = v0;
      *(ushort8v*)(bOut + tid*8) = z;
    }
  } else {
    // raw fp32 (stride OST floats, odd -> conflict-free); maxpool applies
    // (max(raw)-mean)*inv via monotonicity. Node-0 raw == 0 handled by caller.
#pragma unroll
    for (int n = 0; n < NTL; ++n){
      const int m = (nt0 + n)*32 + l31;
      if (m <= 126){
#pragma unroll
        for (int a = 0; a < 2; ++a)
#pragma unroll
          for (int g = 0; g < 4; ++g){
            const int rowb = r0 + a*32 + 8*g + 4*h;
#pragma unroll
            for (int q = 0; q < 4; ++q)
              bOutF[(size_t)(m+1)*OST + rowb + q] = acc[n][a][4*g + q];
          }
      }
    }
  }
  __syncthreads();
}

// LDS: one 66 KB union buffer, reused by every stage:
//   stage          layout                     bytes
//   trees in       [128 n][136] bf16          34816
//   L1 out         [128 n][264] bf16          67584   (over dead trees)
//   L2 out         [128 n][136] bf16          34816   (over dead L1)
//   L3 raw         [128 n][67]  fp32          34304   (over dead L2)
__global__ __launch_bounds__(256, 2) void bao_main(
    const float* __restrict__ trees, const int* __restrict__ gidx,
    const u16* __restrict__ wsW,
    const float* __restrict__ b1, const float* __restrict__ b2, const float* __restrict__ b3,
    const float* __restrict__ W4, const float* __restrict__ b4,
    const float* __restrict__ W5, const float* __restrict__ b5,
    float* __restrict__ dout)
{
  __shared__ __align__(16) u16 buf[33792];      // 67584 B union buffer
  __shared__ int   sidx[384];
  __shared__ float sstat[8];
  __shared__ float spoolP[256];
  __shared__ float spool[64];
  __shared__ float sh[32];

  const int tid = threadIdx.x;
  const int b = blockIdx.x;
  float* bufF = (float*)buf;

  // load + transpose + quantize trees[b] (fp32 [128 c][128 n] -> bf16 buf[n][c]).
  // Packed ds_write_b128; node-stride 17 super-banks => conflict-free.
  const float* tb = trees + (size_t)b * (128*128);
  {
    const int ngrp = tid & 31, cg = tid >> 5;
#pragma unroll
    for (int it = 0; it < 8; ++it){
      const int n  = ngrp + 32*(it & 3);
      const int c0 = (cg + 8*(it >> 2))*8;
      ushort8v pk;
#pragma unroll
      for (int cc = 0; cc < 8; ++cc) pk[cc] = f2bf(tb[(c0 + cc)*128 + n]);
      *(ushort8v*)(buf + n*136 + c0) = pk;
    }
  }
  // idx (381 entries, pad to 384 with 0)
  if (tid < 96){
#pragma unroll
    for (int k = 0; k < 4; ++k){
      int ii = tid*4 + k;
      sidx[ii] = (ii < 381) ? gidx[(size_t)b*381 + ii] : 0;
    }
  }
  __syncthreads();

  float mean, inv;
  do_layer<128,256,136,264,true ,false>(wsW,          b1, buf, buf, nullptr, sidx, sstat, tid, &mean, &inv);
  do_layer<256,128,264,136,true ,false>(wsW + 98304,  b2, buf, buf, nullptr, sidx, sstat, tid, &mean, &inv);
  do_layer<128, 64,136, 67,false,true >(wsW + 196608, b3, buf, nullptr, bufF, sidx, sstat, tid, &mean, &inv);

  // max-pool over nodes (raw fp32, stride 67); node-0 raw is exactly 0 so the
  // 0.f floor is exact. max(normalized) = (max(raw) - mean)*inv (monotone).
  {
    const int ch = tid & 63, seg = tid >> 6;
    float mx = 0.f;
    const int nd0 = seg*32 + (seg == 0 ? 1 : 0);
    for (int nd = nd0; nd < seg*32 + 32; ++nd) mx = fmaxf(mx, bufF[nd*67 + ch]);
    spoolP[seg*64 + ch] = mx;
  }
  __syncthreads();
  if (tid < 64){
    float mx = fmaxf(fmaxf(spoolP[tid], spoolP[64 + tid]),
                     fmaxf(spoolP[128 + tid], spoolP[192 + tid]));
    spool[tid] = (mx - mean) * inv;
  }
  __syncthreads();
  if (tid < 32){
    float a = b4[tid];
    for (int c = 0; c < 64; ++c) a += spool[c] * W4[tid*64 + c];
    sh[tid] = lk(a);
  }
  __syncthreads();
  if (tid == 0){
    float o = b5[0];
    for (int i = 0; i < 32; ++i) o += sh[i] * W5[i];
    dout[b] = o;
  }
}

extern "C" void kernel_launch(void* const* d_in, const int* in_sizes, int n_in,
                              void* d_out, int out_size, void* d_ws, size_t ws_size,
                              hipStream_t stream) {
  const float* trees = (const float*)d_in[0];
  const int*   gidx  = (const int*)d_in[1];
  const float* W1 = (const float*)d_in[2];
  const float* b1 = (const float*)d_in[3];
  const float* W2 = (const float*)d_in[4];
  const float* b2 = (const float*)d_in[5];
  const float* W3 = (const float*)d_in[6];
  const float* b3 = (const float*)d_in[7];
  const float* W4 = (const float*)d_in[8];
  const float* b4 = (const float*)d_in[9];
  const float* W5 = (const float*)d_in[10];
  const float* b5 = (const float*)d_in[11];
  u16* wsW = (u16*)d_ws;   // 221184 bf16 elems = 432 KB of permuted+quantized weights

  permute_w<<<864, 256, 0, stream>>>(W1, W2, W3, wsW);
  bao_main<<<2048, 256, 0, stream>>>(trees, gidx, wsW, b1, b2, b3, W4, b4, W5, b5,
                                     (float*)d_out);
}